// Round 5
// baseline (442.979 us; speedup 1.0000x reference)
//
#include <hip/hip_runtime.h>
#include <math.h>

static constexpr float kNegSlope = 0.2f;
static constexpr float kEps = 1e-16f;

__device__ __forceinline__ float leaky(float v) {
    return v > 0.0f ? v : kNegSlope * v;
}

// ================= bucketed CSR build =================
// Buckets of 32 consecutive dst nodes (bucket = d >> 5). All random writes are
// confined to each bucket's ~2-4 KB region -> lines assembled in L2, no
// partial-line HBM write amplification.

__global__ void k_bzero(int* __restrict__ bcount, int NBUCK) {
    int i = blockIdx.x * blockDim.x + threadIdx.x;
    if (i < NBUCK) bcount[i] = 0;
}

__global__ void k_bcount(const int* __restrict__ ei, int* __restrict__ bcount, int E) {
    int e = blockIdx.x * blockDim.x + threadIdx.x;
    if (e >= E) return;
    atomicAdd(&bcount[ei[E + e] >> 5], 1);
}

// One block, 1024 threads, 4 elements/thread (NBUCK <= 4096).
// bstart[i] = exclusive prefix; bcur[i] = same (bin cursor); bstart[i>=NBUCK] = E.
__global__ void k_bscan(const int* __restrict__ bcount, int* __restrict__ bstart,
                        int* __restrict__ bcur, int* __restrict__ rowptr,
                        int NBUCK, int N, int E) {
    __shared__ int sm[1024];
    int t = threadIdx.x;
    int v[4];
    int s = 0;
#pragma unroll
    for (int j = 0; j < 4; ++j) {
        int idx = 4 * t + j;
        v[j] = (idx < NBUCK) ? bcount[idx] : 0;
        s += v[j];
    }
    sm[t] = s;
    __syncthreads();
    for (int off = 1; off < 1024; off <<= 1) {
        int u = (t >= off) ? sm[t - off] : 0;
        __syncthreads();
        sm[t] += u;
        __syncthreads();
    }
    int run = sm[t] - s;  // exclusive prefix of this thread's chunk
#pragma unroll
    for (int j = 0; j < 4; ++j) {
        int idx = 4 * t + j;
        bstart[idx] = run;
        bcur[idx] = run;
        run += v[j];
    }
    if (t == 0) rowptr[N] = E;
}

__global__ void k_bin(const int* __restrict__ ei, int* __restrict__ bcur,
                      unsigned* __restrict__ sbuf, int E) {
    int e = blockIdx.x * blockDim.x + threadIdx.x;
    if (e >= E) return;
    int s = ei[e], d = ei[E + e];
    int pos = atomicAdd(&bcur[d >> 5], 1);
    sbuf[pos] = (unsigned)s | ((unsigned)(d & 31) << 27);
}

// One 256-thread block per bucket: LDS hist of 32 local nodes -> rowptr for
// those nodes + counting-sort edges into final ssrc (all writes in a ~2KB region).
__global__ void k_bfinal(const unsigned* __restrict__ sbuf, const int* __restrict__ bstart,
                         int* __restrict__ rowptr, int* __restrict__ ssrc, int N) {
    __shared__ int hist[32];
    __shared__ int excl[32];
    __shared__ int cur[32];
    int b = blockIdx.x;
    int t = threadIdx.x;
    int lo = bstart[b], hi = bstart[b + 1];
    if (t < 32) hist[t] = 0;
    __syncthreads();
    for (int i = lo + t; i < hi; i += 256) atomicAdd(&hist[sbuf[i] >> 27], 1);
    __syncthreads();
    if (t == 0) {
        int run = 0;
#pragma unroll
        for (int j = 0; j < 32; ++j) { excl[j] = run; cur[j] = run; run += hist[j]; }
    }
    __syncthreads();
    if (t < 32) {
        int node = (b << 5) + t;
        if (node < N) rowptr[node] = lo + excl[t];
    }
    for (int i = lo + t; i < hi; i += 256) {
        unsigned v = sbuf[i];
        int dl = v >> 27;
        int pos = lo + atomicAdd(&cur[dl], 1);
        ssrc[pos] = (int)(v & 0x07FFFFFFu);
    }
}

// ================= precompute tiny projections =================
// pbuf (32 floats): [0..7]=Ps(d=0), [8..15]=Ps(d=1), [16..23]=Pd(d=0), [24..31]=Pd(d=1)
__global__ void k_precompute(const float* __restrict__ W1, const float* __restrict__ att_src,
                             const float* __restrict__ att_dst, float* __restrict__ pbuf) {
    int t = threadIdx.x;
    if (t >= 32) return;
    int which = t >> 4;          // 0 = src, 1 = dst
    int hd = t & 15;
    int h = hd >> 1, d = hd & 1;
    const float* att = which ? att_dst : att_src;
    float s = 0.0f;
#pragma unroll
    for (int c = 0; c < 16; ++c) s += W1[d * 128 + h * 16 + c] * att[h * 16 + c];
    pbuf[which * 16 + d * 8 + h] = s;
}

// ================= fused layer 1 + transform 2 =================
// thread = (node n, head h). Online softmax on rank-2 features (l, Sx0, Sx1),
// epilogue folds 16 channels into h2[n,:4] partials, shfl-reduced over 8 lanes.
__global__ void k_gather1(const int* __restrict__ rowptr, const int* __restrict__ ssrc,
                          const float* __restrict__ x, const float* __restrict__ pbuf,
                          const float* __restrict__ W1, const float* __restrict__ b1,
                          const float* __restrict__ W2, const float* __restrict__ att_src2,
                          const float* __restrict__ att_dst2, float* __restrict__ h2,
                          float* __restrict__ a2s, float* __restrict__ a2d, int N) {
    int t = blockIdx.x * blockDim.x + threadIdx.x;
    int n = t >> 3, h = t & 7;
    bool active = (n < N);
    float Ps0 = pbuf[h], Ps1 = pbuf[8 + h];
    float Pd0 = pbuf[16 + h], Pd1 = pbuf[24 + h];
    float m = -INFINITY, l = 0.0f, sx0 = 0.0f, sx1 = 0.0f;
    if (active) {
        float2 xn = ((const float2*)x)[n];
        float ad = xn.x * Pd0 + xn.y * Pd1;
        int start = rowptr[n], end = rowptr[n + 1];
        for (int j = start; j < end; ++j) {
            int src = ssrc[j];
            float2 xs = ((const float2*)x)[src];
            float e = leaky(xs.x * Ps0 + xs.y * Ps1 + ad);
            if (e > m) {
                float sc = __expf(m - e);  // m=-inf -> 0
                l *= sc; sx0 *= sc; sx1 *= sc;
                m = e;
            }
            float p = __expf(e - m);
            l += p;
            sx0 += p * xs.x;
            sx1 += p * xs.y;
        }
    }
    float inv = 1.0f / (l + kEps);
    float sX0 = sx0 * inv, sX1 = sx1 * inv;
    float h0 = 0.f, h1v = 0.f, h2v = 0.f, h3 = 0.f;
#pragma unroll
    for (int c = 0; c < 16; ++c) {
        int col = h * 16 + c;
        float o = fmaxf(W1[col] * sX0 + W1[128 + col] * sX1 + b1[col], 0.0f);
        h0 += o * W2[col * 4 + 0];
        h1v += o * W2[col * 4 + 1];
        h2v += o * W2[col * 4 + 2];
        h3 += o * W2[col * 4 + 3];
    }
#pragma unroll
    for (int off = 1; off < 8; off <<= 1) {
        h0 += __shfl_xor(h0, off);
        h1v += __shfl_xor(h1v, off);
        h2v += __shfl_xor(h2v, off);
        h3 += __shfl_xor(h3, off);
    }
    if (active && h == 0) {
        ((float4*)h2)[n] = make_float4(h0, h1v, h2v, h3);
        a2s[n] = h0 * att_src2[0] + h1v * att_src2[1] + h2v * att_src2[2] + h3 * att_src2[3];
        a2d[n] = h0 * att_dst2[0] + h1v * att_dst2[1] + h2v * att_dst2[2] + h3 * att_dst2[3];
    }
}

// ================= layer 2 gather + log_softmax =================
__global__ void k_gather2_out(const int* __restrict__ rowptr, const int* __restrict__ ssrc,
                              const float* __restrict__ a2s, const float* __restrict__ a2d,
                              const float* __restrict__ h2, const float* __restrict__ b2,
                              float* __restrict__ out, int N) {
    int n = blockIdx.x * blockDim.x + threadIdx.x;
    if (n >= N) return;
    int start = rowptr[n], end = rowptr[n + 1];
    float ad = a2d[n];
    float m = -INFINITY, l = 0.0f;
    float4 acc = make_float4(0.f, 0.f, 0.f, 0.f);
    for (int j = start; j < end; ++j) {
        int src = ssrc[j];
        float e = leaky(a2s[src] + ad);
        float4 hv = ((const float4*)h2)[src];
        if (e > m) {
            float sc = __expf(m - e);
            acc.x *= sc; acc.y *= sc; acc.z *= sc; acc.w *= sc;
            l *= sc;
            m = e;
        }
        float p = __expf(e - m);
        l += p;
        acc.x += p * hv.x; acc.y += p * hv.y; acc.z += p * hv.z; acc.w += p * hv.w;
    }
    float inv = 1.0f / (l + kEps);
    float4 v = make_float4(acc.x * inv + b2[0], acc.y * inv + b2[1],
                           acc.z * inv + b2[2], acc.w * inv + b2[3]);
    float mx = fmaxf(fmaxf(v.x, v.y), fmaxf(v.z, v.w));
    float sum = __expf(v.x - mx) + __expf(v.y - mx) + __expf(v.z - mx) + __expf(v.w - mx);
    float lse = mx + logf(sum);
    ((float4*)out)[n] = make_float4(v.x - lse, v.y - lse, v.z - lse, v.w - lse);
}

extern "C" void kernel_launch(void* const* d_in, const int* in_sizes, int n_in,
                              void* d_out, int out_size, void* d_ws, size_t ws_size,
                              hipStream_t stream) {
    const float* x        = (const float*)d_in[0];
    const int*   ei       = (const int*)d_in[1];
    const float* W1       = (const float*)d_in[2];
    const float* att_src1 = (const float*)d_in[3];
    const float* att_dst1 = (const float*)d_in[4];
    const float* b1       = (const float*)d_in[5];
    const float* W2       = (const float*)d_in[6];
    const float* att_src2 = (const float*)d_in[7];
    const float* att_dst2 = (const float*)d_in[8];
    const float* b2       = (const float*)d_in[9];

    const int N = in_sizes[0] / 2;     // x is [N,2]
    const int E = in_sizes[1] / 2;     // edge_index is [2,E]
    const int NBUCK = (N + 31) / 32;   // 32-node buckets (<= 4096)

    // ---- workspace layout (all 4B elems; chunk sizes multiples of 4) ----
    int* bcount = (int*)d_ws;             // 4096
    int* bstart = bcount + 4096;          // 4097 -> pad 4100
    int* bcur   = bstart + 4100;          // 4096
    int* rowptr = bcur + 4096;            // N+1 -> pad N+4
    int* ssrc   = rowptr + N + 4;         // E
    unsigned* sbuf = (unsigned*)(ssrc + E);  // E
    float* pbuf = (float*)(sbuf + E);     // 32
    float* h2   = pbuf + 32;              // N*4
    float* a2s  = h2 + (size_t)N * 4;     // N
    float* a2d  = a2s + N;                // N

    const int T = 256;

    // bucketed CSR build (by destination)
    k_bzero<<<(4096 + T - 1) / T, T, 0, stream>>>(bcount, NBUCK);
    k_bcount<<<(E + T - 1) / T, T, 0, stream>>>(ei, bcount, E);
    k_bscan<<<1, 1024, 0, stream>>>(bcount, bstart, bcur, rowptr, NBUCK, N, E);
    k_bin<<<(E + T - 1) / T, T, 0, stream>>>(ei, bcur, sbuf, E);
    k_bfinal<<<NBUCK, T, 0, stream>>>(sbuf, bstart, rowptr, ssrc, N);

    // tiny projections
    k_precompute<<<1, 64, 0, stream>>>(W1, att_src1, att_dst1, pbuf);

    // fused layer 1 + transform 2
    k_gather1<<<(N * 8 + T - 1) / T, T, 0, stream>>>(rowptr, ssrc, x, pbuf, W1, b1, W2,
                                                     att_src2, att_dst2, h2, a2s, a2d, N);

    // layer 2 gather + log_softmax
    k_gather2_out<<<(N + T - 1) / T, T, 0, stream>>>(rowptr, ssrc, a2s, a2d, h2, b2,
                                                     (float*)d_out, N);
}

// Round 6
// 223.597 us; speedup vs baseline: 1.9812x; 1.9812x over previous
//
#include <hip/hip_runtime.h>
#include <math.h>

static constexpr float kNegSlope = 0.2f;
static constexpr float kEps = 1e-16f;
static constexpr int BINB = 64;      // partition blocks for hist/bin passes
static constexpr int MAXBUCK = 4096; // LDS capacity for bucket counters

__device__ __forceinline__ float leaky(float v) {
    return v > 0.0f ? v : kNegSlope * v;
}

// ================= atomic-free bucketed CSR build =================
// bucket = dst >> 5 (32 nodes per bucket). Radix-partition style:
// per-block private LDS histograms -> global scan of table[bucket][blk] ->
// deterministic scatter with LDS cursors. NO global atomics anywhere.

// Pass 1: block b histograms its contiguous edge slice into LDS, writes its
// column of table (bucket-major: table[bucket*BINB + b]).
__global__ void k_hist1(const int* __restrict__ ei, int* __restrict__ table,
                        int E, int NBUCK) {
    __shared__ int hist[MAXBUCK];
    int b = blockIdx.x, t = threadIdx.x;
    for (int i = t; i < NBUCK; i += 1024) hist[i] = 0;
    __syncthreads();
    int S = (E + BINB - 1) / BINB;
    int lo = b * S, hi = min(lo + S, E);
    for (int i = lo + t; i < hi; i += 1024) atomicAdd(&hist[ei[E + i] >> 5], 1);
    __syncthreads();
    for (int i = t; i < NBUCK; i += 1024) table[i * BINB + b] = hist[i];
}

// Generic hierarchical exclusive scan (3 kernels) over n ints.
__global__ void k_scan_reduce(const int* __restrict__ src, int* __restrict__ partial, int n) {
    __shared__ int sm[1024];
    int t = threadIdx.x;
    int i = blockIdx.x * 1024 + t;
    sm[t] = (i < n) ? src[i] : 0;
    __syncthreads();
#pragma unroll
    for (int off = 512; off > 0; off >>= 1) {
        if (t < off) sm[t] += sm[t + off];
        __syncthreads();
    }
    if (t == 0) partial[blockIdx.x] = sm[0];
}

__global__ void k_scan_top(int* __restrict__ partial, int NB) {
    __shared__ int sm[1024];
    int t = threadIdx.x;
    int v = (t < NB) ? partial[t] : 0;
    sm[t] = v;
    __syncthreads();
    for (int off = 1; off < 1024; off <<= 1) {
        int u = (t >= off) ? sm[t - off] : 0;
        __syncthreads();
        sm[t] += u;
        __syncthreads();
    }
    if (t < NB) partial[t] = sm[t] - v;  // exclusive
}

__global__ void k_scan_final(int* __restrict__ data, const int* __restrict__ partial, int n) {
    __shared__ int sm[1024];
    int t = threadIdx.x;
    int i = blockIdx.x * 1024 + t;
    int v = (i < n) ? data[i] : 0;
    sm[t] = v;
    __syncthreads();
    for (int off = 1; off < 1024; off <<= 1) {
        int u = (t >= off) ? sm[t - off] : 0;
        __syncthreads();
        sm[t] += u;
        __syncthreads();
    }
    if (i < n) data[i] = sm[t] - v + partial[blockIdx.x];
}

// bstart[bucket] = scanned table at (bucket, blk=0); plus sentinels.
__global__ void k_extract(const int* __restrict__ table, int* __restrict__ bstart,
                          int* __restrict__ rowptr, int NBUCK, int N, int E) {
    int i = blockIdx.x * blockDim.x + threadIdx.x;
    if (i < NBUCK) bstart[i] = table[i * BINB];
    if (i == 0) { bstart[NBUCK] = E; rowptr[N] = E; }
}

// Pass 2: block b loads its column of scanned bases into LDS cursors, then
// streams its slice writing each edge to its deterministic global position.
__global__ void k_bin2(const int* __restrict__ ei, const int* __restrict__ table,
                       unsigned* __restrict__ sbuf, int E, int NBUCK) {
    __shared__ int cur[MAXBUCK];
    int b = blockIdx.x, t = threadIdx.x;
    for (int i = t; i < NBUCK; i += 1024) cur[i] = table[i * BINB + b];
    __syncthreads();
    int S = (E + BINB - 1) / BINB;
    int lo = b * S, hi = min(lo + S, E);
    for (int i = lo + t; i < hi; i += 1024) {
        int s = ei[i], d = ei[E + i];
        int pos = atomicAdd(&cur[d >> 5], 1);  // LDS atomic only
        sbuf[pos] = (unsigned)s | ((unsigned)(d & 31) << 27);
    }
}

// One block per bucket: LDS hist of 32 local nodes -> rowptr + within-bucket
// counting sort into final ssrc (all writes in a ~2KB single-writer region).
__global__ void k_bfinal(const unsigned* __restrict__ sbuf, const int* __restrict__ bstart,
                         int* __restrict__ rowptr, int* __restrict__ ssrc, int N) {
    __shared__ int hist[32];
    __shared__ int excl[32];
    __shared__ int cur[32];
    int b = blockIdx.x;
    int t = threadIdx.x;
    int lo = bstart[b], hi = bstart[b + 1];
    if (t < 32) hist[t] = 0;
    __syncthreads();
    for (int i = lo + t; i < hi; i += 256) atomicAdd(&hist[sbuf[i] >> 27], 1);
    __syncthreads();
    if (t == 0) {
        int run = 0;
#pragma unroll
        for (int j = 0; j < 32; ++j) { excl[j] = run; cur[j] = run; run += hist[j]; }
    }
    __syncthreads();
    if (t < 32) {
        int node = (b << 5) + t;
        if (node < N) rowptr[node] = lo + excl[t];
    }
    for (int i = lo + t; i < hi; i += 256) {
        unsigned v = sbuf[i];
        int dl = v >> 27;
        int pos = lo + atomicAdd(&cur[dl], 1);
        ssrc[pos] = (int)(v & 0x07FFFFFFu);
    }
}

// ================= precompute tiny projections =================
// pbuf (32 floats): [0..7]=Ps(d=0), [8..15]=Ps(d=1), [16..23]=Pd(d=0), [24..31]=Pd(d=1)
__global__ void k_precompute(const float* __restrict__ W1, const float* __restrict__ att_src,
                             const float* __restrict__ att_dst, float* __restrict__ pbuf) {
    int t = threadIdx.x;
    if (t >= 32) return;
    int which = t >> 4;          // 0 = src, 1 = dst
    int hd = t & 15;
    int h = hd >> 1, d = hd & 1;
    const float* att = which ? att_dst : att_src;
    float s = 0.0f;
#pragma unroll
    for (int c = 0; c < 16; ++c) s += W1[d * 128 + h * 16 + c] * att[h * 16 + c];
    pbuf[which * 16 + d * 8 + h] = s;
}

// ================= fused layer 1 + transform 2 =================
// thread = (node n, head h). Online softmax on rank-2 features (l, Sx0, Sx1),
// epilogue folds 16 channels into h2[n,:4] partials, shfl-reduced over 8 lanes.
__global__ void k_gather1(const int* __restrict__ rowptr, const int* __restrict__ ssrc,
                          const float* __restrict__ x, const float* __restrict__ pbuf,
                          const float* __restrict__ W1, const float* __restrict__ b1,
                          const float* __restrict__ W2, const float* __restrict__ att_src2,
                          const float* __restrict__ att_dst2, float* __restrict__ h2,
                          float* __restrict__ a2s, float* __restrict__ a2d, int N) {
    int t = blockIdx.x * blockDim.x + threadIdx.x;
    int n = t >> 3, h = t & 7;
    bool active = (n < N);
    float Ps0 = pbuf[h], Ps1 = pbuf[8 + h];
    float Pd0 = pbuf[16 + h], Pd1 = pbuf[24 + h];
    float m = -INFINITY, l = 0.0f, sx0 = 0.0f, sx1 = 0.0f;
    if (active) {
        float2 xn = ((const float2*)x)[n];
        float ad = xn.x * Pd0 + xn.y * Pd1;
        int start = rowptr[n], end = rowptr[n + 1];
        for (int j = start; j < end; ++j) {
            int src = ssrc[j];
            float2 xs = ((const float2*)x)[src];
            float e = leaky(xs.x * Ps0 + xs.y * Ps1 + ad);
            if (e > m) {
                float sc = __expf(m - e);  // m=-inf -> 0
                l *= sc; sx0 *= sc; sx1 *= sc;
                m = e;
            }
            float p = __expf(e - m);
            l += p;
            sx0 += p * xs.x;
            sx1 += p * xs.y;
        }
    }
    float inv = 1.0f / (l + kEps);
    float sX0 = sx0 * inv, sX1 = sx1 * inv;
    float h0 = 0.f, h1v = 0.f, h2v = 0.f, h3 = 0.f;
#pragma unroll
    for (int c = 0; c < 16; ++c) {
        int col = h * 16 + c;
        float o = fmaxf(W1[col] * sX0 + W1[128 + col] * sX1 + b1[col], 0.0f);
        h0 += o * W2[col * 4 + 0];
        h1v += o * W2[col * 4 + 1];
        h2v += o * W2[col * 4 + 2];
        h3 += o * W2[col * 4 + 3];
    }
#pragma unroll
    for (int off = 1; off < 8; off <<= 1) {
        h0 += __shfl_xor(h0, off);
        h1v += __shfl_xor(h1v, off);
        h2v += __shfl_xor(h2v, off);
        h3 += __shfl_xor(h3, off);
    }
    if (active && h == 0) {
        ((float4*)h2)[n] = make_float4(h0, h1v, h2v, h3);
        a2s[n] = h0 * att_src2[0] + h1v * att_src2[1] + h2v * att_src2[2] + h3 * att_src2[3];
        a2d[n] = h0 * att_dst2[0] + h1v * att_dst2[1] + h2v * att_dst2[2] + h3 * att_dst2[3];
    }
}

// ================= layer 2 gather + log_softmax =================
__global__ void k_gather2_out(const int* __restrict__ rowptr, const int* __restrict__ ssrc,
                              const float* __restrict__ a2s, const float* __restrict__ a2d,
                              const float* __restrict__ h2, const float* __restrict__ b2,
                              float* __restrict__ out, int N) {
    int n = blockIdx.x * blockDim.x + threadIdx.x;
    if (n >= N) return;
    int start = rowptr[n], end = rowptr[n + 1];
    float ad = a2d[n];
    float m = -INFINITY, l = 0.0f;
    float4 acc = make_float4(0.f, 0.f, 0.f, 0.f);
    for (int j = start; j < end; ++j) {
        int src = ssrc[j];
        float e = leaky(a2s[src] + ad);
        float4 hv = ((const float4*)h2)[src];
        if (e > m) {
            float sc = __expf(m - e);
            acc.x *= sc; acc.y *= sc; acc.z *= sc; acc.w *= sc;
            l *= sc;
            m = e;
        }
        float p = __expf(e - m);
        l += p;
        acc.x += p * hv.x; acc.y += p * hv.y; acc.z += p * hv.z; acc.w += p * hv.w;
    }
    float inv = 1.0f / (l + kEps);
    float4 v = make_float4(acc.x * inv + b2[0], acc.y * inv + b2[1],
                           acc.z * inv + b2[2], acc.w * inv + b2[3]);
    float mx = fmaxf(fmaxf(v.x, v.y), fmaxf(v.z, v.w));
    float sum = __expf(v.x - mx) + __expf(v.y - mx) + __expf(v.z - mx) + __expf(v.w - mx);
    float lse = mx + logf(sum);
    ((float4*)out)[n] = make_float4(v.x - lse, v.y - lse, v.z - lse, v.w - lse);
}

extern "C" void kernel_launch(void* const* d_in, const int* in_sizes, int n_in,
                              void* d_out, int out_size, void* d_ws, size_t ws_size,
                              hipStream_t stream) {
    const float* x        = (const float*)d_in[0];
    const int*   ei       = (const int*)d_in[1];
    const float* W1       = (const float*)d_in[2];
    const float* att_src1 = (const float*)d_in[3];
    const float* att_dst1 = (const float*)d_in[4];
    const float* b1       = (const float*)d_in[5];
    const float* W2       = (const float*)d_in[6];
    const float* att_src2 = (const float*)d_in[7];
    const float* att_dst2 = (const float*)d_in[8];
    const float* b2       = (const float*)d_in[9];

    const int N = in_sizes[0] / 2;     // x is [N,2]
    const int E = in_sizes[1] / 2;     // edge_index is [2,E]
    const int NBUCK = (N + 31) / 32;   // 32-node buckets (<= MAXBUCK)
    const int ntable = NBUCK * BINB;   // bucket-major (bucket, blk) counts
    const int nsb = (ntable + 1023) / 1024;  // scan blocks for table

    // ---- workspace layout (4B elems; all chunk sizes multiples of 4) ----
    int* table   = (int*)d_ws;                      // ntable (+64 pad)
    int* partial = table + ntable + 64;             // 1024
    int* bstart  = partial + 1024;                  // NBUCK+1 -> pad
    int* rowptr  = bstart + ((NBUCK + 1 + 3) & ~3); // N+1 -> pad
    int* ssrc    = rowptr + ((N + 1 + 3) & ~3);     // E
    unsigned* sbuf = (unsigned*)(ssrc + E);         // E
    float* pbuf  = (float*)(sbuf + E);              // 32
    float* h2    = pbuf + 32;                       // N*4
    float* a2s   = h2 + (size_t)N * 4;              // N
    float* a2d   = a2s + N;                         // N

    const int T = 256;

    // atomic-free CSR build (by destination)
    k_hist1<<<BINB, 1024, 0, stream>>>(ei, table, E, NBUCK);
    k_scan_reduce<<<nsb, 1024, 0, stream>>>(table, partial, ntable);
    k_scan_top<<<1, 1024, 0, stream>>>(partial, nsb);
    k_scan_final<<<nsb, 1024, 0, stream>>>(table, partial, ntable);
    k_extract<<<(NBUCK + T - 1) / T, T, 0, stream>>>(table, bstart, rowptr, NBUCK, N, E);
    k_bin2<<<BINB, 1024, 0, stream>>>(ei, table, sbuf, E, NBUCK);
    k_bfinal<<<NBUCK, T, 0, stream>>>(sbuf, bstart, rowptr, ssrc, N);

    // tiny projections
    k_precompute<<<1, 64, 0, stream>>>(W1, att_src1, att_dst1, pbuf);

    // fused layer 1 + transform 2
    k_gather1<<<(N * 8 + T - 1) / T, T, 0, stream>>>(rowptr, ssrc, x, pbuf, W1, b1, W2,
                                                     att_src2, att_dst2, h2, a2s, a2d, N);

    // layer 2 gather + log_softmax
    k_gather2_out<<<(N + T - 1) / T, T, 0, stream>>>(rowptr, ssrc, a2s, a2d, h2, b2,
                                                     (float*)d_out, N);
}

// Round 7
// 203.015 us; speedup vs baseline: 2.1820x; 1.1014x over previous
//
#include <hip/hip_runtime.h>
#include <math.h>

static constexpr float kNegSlope = 0.2f;
static constexpr float kEps = 1e-16f;
static constexpr int BINB = 256;       // partition blocks for hist/bin passes
static constexpr int BSHIFT = 7;       // 128 nodes per bucket
static constexpr int BMASK = 127;
static constexpr unsigned SRCMASK = 0x1FFFFu;  // 17 bits (N < 131072)

__device__ __forceinline__ float leaky(float v) {
    return v > 0.0f ? v : kNegSlope * v;
}

// ================= atomic-free bucketed CSR build =================
// bucket = dst >> 7 (128 nodes). Radix-partition: per-block private LDS
// histograms -> scan of table[bucket][blk] -> deterministic scatter with LDS
// cursors. NO global atomics anywhere. Record: src | (d&127)<<17 (24 bits).

__global__ void k_hist1(const int* __restrict__ ei, int* __restrict__ table,
                        int E, int NBUCK) {
    __shared__ int hist[1024];
    int b = blockIdx.x, t = threadIdx.x;
    for (int i = t; i < NBUCK; i += 512) hist[i] = 0;
    __syncthreads();
    int S = (E + BINB - 1) / BINB;
    int lo = b * S, hi = min(lo + S, E);
    for (int i = lo + t; i < hi; i += 512) atomicAdd(&hist[ei[E + i] >> BSHIFT], 1);
    __syncthreads();
    for (int i = t; i < NBUCK; i += 512) table[i * BINB + b] = hist[i];
}

// Generic hierarchical exclusive scan (3 kernels) over n ints.
__global__ void k_scan_reduce(const int* __restrict__ src, int* __restrict__ partial, int n) {
    __shared__ int sm[1024];
    int t = threadIdx.x;
    int i = blockIdx.x * 1024 + t;
    sm[t] = (i < n) ? src[i] : 0;
    __syncthreads();
#pragma unroll
    for (int off = 512; off > 0; off >>= 1) {
        if (t < off) sm[t] += sm[t + off];
        __syncthreads();
    }
    if (t == 0) partial[blockIdx.x] = sm[0];
}

__global__ void k_scan_top(int* __restrict__ partial, int NB,
                           int* __restrict__ rowptr, int N, int E) {
    __shared__ int sm[1024];
    int t = threadIdx.x;
    int v = (t < NB) ? partial[t] : 0;
    sm[t] = v;
    __syncthreads();
    for (int off = 1; off < 1024; off <<= 1) {
        int u = (t >= off) ? sm[t - off] : 0;
        __syncthreads();
        sm[t] += u;
        __syncthreads();
    }
    if (t < NB) partial[t] = sm[t] - v;  // exclusive
    if (t == 0) rowptr[N] = E;
}

__global__ void k_scan_final(int* __restrict__ data, const int* __restrict__ partial, int n) {
    __shared__ int sm[1024];
    int t = threadIdx.x;
    int i = blockIdx.x * 1024 + t;
    int v = (i < n) ? data[i] : 0;
    sm[t] = v;
    __syncthreads();
    for (int off = 1; off < 1024; off <<= 1) {
        int u = (t >= off) ? sm[t - off] : 0;
        __syncthreads();
        sm[t] += u;
        __syncthreads();
    }
    if (i < n) data[i] = sm[t] - v + partial[blockIdx.x];
}

__global__ void k_bin2(const int* __restrict__ ei, const int* __restrict__ table,
                       unsigned* __restrict__ sbuf, int E, int NBUCK) {
    __shared__ int cur[1024];
    int b = blockIdx.x, t = threadIdx.x;
    for (int i = t; i < NBUCK; i += 512) cur[i] = table[i * BINB + b];
    __syncthreads();
    int S = (E + BINB - 1) / BINB;
    int lo = b * S, hi = min(lo + S, E);
    for (int i = lo + t; i < hi; i += 512) {
        int s = ei[i], d = ei[E + i];
        int pos = atomicAdd(&cur[d >> BSHIFT], 1);  // LDS atomic only
        sbuf[pos] = (unsigned)s | ((unsigned)(d & BMASK) << 17);
    }
}

// ================= precompute tiny projections =================
// pbuf (32 floats): [0..7]=Ps(d=0), [8..15]=Ps(d=1), [16..23]=Pd(d=0), [24..31]=Pd(d=1)
__global__ void k_precompute(const float* __restrict__ W1, const float* __restrict__ att_src,
                             const float* __restrict__ att_dst, float* __restrict__ pbuf) {
    int t = threadIdx.x;
    if (t >= 32) return;
    int which = t >> 4;          // 0 = src, 1 = dst
    int hd = t & 15;
    int h = hd >> 1, d = hd & 1;
    const float* att = which ? att_dst : att_src;
    float s = 0.0f;
#pragma unroll
    for (int c = 0; c < 16; ++c) s += W1[d * 128 + h * 16 + c] * att[h * 16 + c];
    pbuf[which * 16 + d * 8 + h] = s;
}

// ================= bucket finalize + fused layer-1 gather =================
// One 1024-thread block per 128-node bucket.
// Phase 1: LDS hist of the 128 local nodes over the bucket's sbuf range.
// Phase 2: rowptr + counting-sort src into ssrc (single-writer ~8KB region).
// Phase 3: thread=(dl,h): rank-2 online softmax + W2 fold + shfl epilogue.
__global__ void k_bfinal_g1(const unsigned* __restrict__ sbuf, const int* __restrict__ table,
                            int* __restrict__ rowptr, int* __restrict__ ssrc,
                            const float* __restrict__ x, const float* __restrict__ pbuf,
                            const float* __restrict__ W1, const float* __restrict__ b1,
                            const float* __restrict__ W2, const float* __restrict__ att_src2,
                            const float* __restrict__ att_dst2, float* __restrict__ h2,
                            float* __restrict__ a2s, float* __restrict__ a2d,
                            int N, int E, int NBUCK) {
    __shared__ int hist[128];
    __shared__ int excl[128];
    __shared__ int cur[128];
    int b = blockIdx.x;
    int t = threadIdx.x;
    int lo = table[b * BINB];
    int hi = (b + 1 < NBUCK) ? table[(b + 1) * BINB] : E;
    if (t < 128) hist[t] = 0;
    __syncthreads();
    for (int i = lo + t; i < hi; i += 1024) atomicAdd(&hist[sbuf[i] >> 17], 1);
    __syncthreads();
    if (t == 0) {
        int run = 0;
#pragma unroll
        for (int j = 0; j < 128; ++j) { excl[j] = run; cur[j] = run; run += hist[j]; }
    }
    __syncthreads();
    if (t < 128) {
        int node = (b << BSHIFT) + t;
        if (node < N) rowptr[node] = lo + excl[t];
    }
    for (int i = lo + t; i < hi; i += 1024) {
        unsigned v = sbuf[i];
        int dl = v >> 17;
        int pos = lo + atomicAdd(&cur[dl], 1);
        ssrc[pos] = (int)(v & SRCMASK);
    }
    __syncthreads();  // drains vmem (vmcnt 0) before barrier -> ssrc visible via same-CU L2

    // ---- fused gather (layer 1 + transform 2) ----
    int dl = t >> 3, h = t & 7;
    int node = (b << BSHIFT) + dl;
    bool active = (node < N);
    float Ps0 = pbuf[h], Ps1 = pbuf[8 + h];
    float Pd0 = pbuf[16 + h], Pd1 = pbuf[24 + h];
    float m = -INFINITY, l = 0.0f, sx0 = 0.0f, sx1 = 0.0f;
    if (active) {
        float2 xn = ((const float2*)x)[node];
        float ad = xn.x * Pd0 + xn.y * Pd1;
        int start = lo + excl[dl];
        int end = start + hist[dl];
        for (int j = start; j < end; ++j) {
            int src = ssrc[j];
            float2 xs = ((const float2*)x)[src];
            float e = leaky(xs.x * Ps0 + xs.y * Ps1 + ad);
            if (e > m) {
                float sc = __expf(m - e);  // m=-inf -> 0
                l *= sc; sx0 *= sc; sx1 *= sc;
                m = e;
            }
            float p = __expf(e - m);
            l += p;
            sx0 += p * xs.x;
            sx1 += p * xs.y;
        }
    }
    float inv = 1.0f / (l + kEps);
    float sX0 = sx0 * inv, sX1 = sx1 * inv;
    float h0 = 0.f, h1v = 0.f, h2v = 0.f, h3 = 0.f;
#pragma unroll
    for (int c = 0; c < 16; ++c) {
        int col = h * 16 + c;
        float o = fmaxf(W1[col] * sX0 + W1[128 + col] * sX1 + b1[col], 0.0f);
        h0 += o * W2[col * 4 + 0];
        h1v += o * W2[col * 4 + 1];
        h2v += o * W2[col * 4 + 2];
        h3 += o * W2[col * 4 + 3];
    }
#pragma unroll
    for (int off = 1; off < 8; off <<= 1) {
        h0 += __shfl_xor(h0, off);
        h1v += __shfl_xor(h1v, off);
        h2v += __shfl_xor(h2v, off);
        h3 += __shfl_xor(h3, off);
    }
    if (active && h == 0) {
        ((float4*)h2)[node] = make_float4(h0, h1v, h2v, h3);
        a2s[node] = h0 * att_src2[0] + h1v * att_src2[1] + h2v * att_src2[2] + h3 * att_src2[3];
        a2d[node] = h0 * att_dst2[0] + h1v * att_dst2[1] + h2v * att_dst2[2] + h3 * att_dst2[3];
    }
}

// ================= layer 2 gather + log_softmax =================
__global__ void k_gather2_out(const int* __restrict__ rowptr, const int* __restrict__ ssrc,
                              const float* __restrict__ a2s, const float* __restrict__ a2d,
                              const float* __restrict__ h2, const float* __restrict__ b2,
                              float* __restrict__ out, int N) {
    int n = blockIdx.x * blockDim.x + threadIdx.x;
    if (n >= N) return;
    int start = rowptr[n], end = rowptr[n + 1];
    float ad = a2d[n];
    float m = -INFINITY, l = 0.0f;
    float4 acc = make_float4(0.f, 0.f, 0.f, 0.f);
    for (int j = start; j < end; ++j) {
        int src = ssrc[j];
        float e = leaky(a2s[src] + ad);
        float4 hv = ((const float4*)h2)[src];
        if (e > m) {
            float sc = __expf(m - e);
            acc.x *= sc; acc.y *= sc; acc.z *= sc; acc.w *= sc;
            l *= sc;
            m = e;
        }
        float p = __expf(e - m);
        l += p;
        acc.x += p * hv.x; acc.y += p * hv.y; acc.z += p * hv.z; acc.w += p * hv.w;
    }
    float inv = 1.0f / (l + kEps);
    float4 v = make_float4(acc.x * inv + b2[0], acc.y * inv + b2[1],
                           acc.z * inv + b2[2], acc.w * inv + b2[3]);
    float mx = fmaxf(fmaxf(v.x, v.y), fmaxf(v.z, v.w));
    float sum = __expf(v.x - mx) + __expf(v.y - mx) + __expf(v.z - mx) + __expf(v.w - mx);
    float lse = mx + logf(sum);
    ((float4*)out)[n] = make_float4(v.x - lse, v.y - lse, v.z - lse, v.w - lse);
}

extern "C" void kernel_launch(void* const* d_in, const int* in_sizes, int n_in,
                              void* d_out, int out_size, void* d_ws, size_t ws_size,
                              hipStream_t stream) {
    const float* x        = (const float*)d_in[0];
    const int*   ei       = (const int*)d_in[1];
    const float* W1       = (const float*)d_in[2];
    const float* att_src1 = (const float*)d_in[3];
    const float* att_dst1 = (const float*)d_in[4];
    const float* b1       = (const float*)d_in[5];
    const float* W2       = (const float*)d_in[6];
    const float* att_src2 = (const float*)d_in[7];
    const float* att_dst2 = (const float*)d_in[8];
    const float* b2       = (const float*)d_in[9];

    const int N = in_sizes[0] / 2;           // x is [N,2]
    const int E = in_sizes[1] / 2;           // edge_index is [2,E]
    const int NBUCK = (N + BMASK) >> BSHIFT; // 128-node buckets (<= 1024)
    const int ntable = NBUCK * BINB;
    const int nsb = (ntable + 1023) / 1024;  // scan blocks (<= 1024)

    // ---- workspace layout (4B elems) ----
    int* table   = (int*)d_ws;                    // ntable (+64 pad)
    int* partial = table + ntable + 64;           // 1024
    int* rowptr  = partial + 1024;                // N+1 -> pad N+4
    int* ssrc    = rowptr + ((N + 4) & ~3);       // E
    unsigned* sbuf = (unsigned*)(ssrc + E);       // E
    float* pbuf  = (float*)(sbuf + E);            // 32
    float* h2    = pbuf + 32;                     // N*4
    float* a2s   = h2 + (size_t)N * 4;            // N
    float* a2d   = a2s + N;                       // N

    // tiny projections (no deps on CSR)
    k_precompute<<<1, 64, 0, stream>>>(W1, att_src1, att_dst1, pbuf);

    // atomic-free CSR build (by destination)
    k_hist1<<<BINB, 512, 0, stream>>>(ei, table, E, NBUCK);
    k_scan_reduce<<<nsb, 1024, 0, stream>>>(table, partial, ntable);
    k_scan_top<<<1, 1024, 0, stream>>>(partial, nsb, rowptr, N, E);
    k_scan_final<<<nsb, 1024, 0, stream>>>(table, partial, ntable);
    k_bin2<<<BINB, 512, 0, stream>>>(ei, table, sbuf, E, NBUCK);

    // finalize buckets + fused layer 1 + transform 2
    k_bfinal_g1<<<NBUCK, 1024, 0, stream>>>(sbuf, table, rowptr, ssrc, x, pbuf, W1, b1,
                                            W2, att_src2, att_dst2, h2, a2s, a2d,
                                            N, E, NBUCK);

    // layer 2 gather + log_softmax
    k_gather2_out<<<(N + 255) / 256, 256, 0, stream>>>(rowptr, ssrc, a2s, a2d, h2, b2,
                                                       (float*)d_out, N);
}